// Round 6
// baseline (142.631 us; speedup 1.0000x reference)
//
#include <hip/hip_runtime.h>

// Dist_Conv2D_Dense: Chebyshev (L-inf) distance "conv".
// B=8, Cin=16, H=W=64, Cout=32, K=3, stride=1, edge-replicate pad.
//
// Round-6: INSTRUMENTED round-4 structure. The harness's 256MB ws re-poison
// fill (~40us) hides our kernel from rocprof top-5; REPS=8 in-kernel
// repetition (opaque pointers prevent cross-rep CSE/DSE) lifts the dispatch
// above the fills so we finally get its counter row. dur/8 ~= warm kernel.

constexpr int Bn = 8, Cin = 16, Hn = 64, Wn = 64, Cout = 32;
constexpr int CPT = 4;            // couts per thread
constexpr int NG  = Cout / CPT;   // 8 cout groups
constexpr int BLOCK = 256;
constexpr int REPS = 8;           // instrumentation: repeat compute in-kernel

__global__ __launch_bounds__(BLOCK, 2)   // 2 waves/EU floor -> 256-VGPR cap, no spill risk
void dist_conv_kernel(const float* __restrict__ x,
                      const float* __restrict__ wt,
                      const float* __restrict__ bias,
                      float* __restrict__ out) {
    // weights for this block's 4 couts: [cin*9 + k] -> float4 over couts
    __shared__ float4 wl[Cin * 9];

    const int g    = blockIdx.x & (NG - 1);   // cout group 0..7
    const int pblk = blockIdx.x >> 3;         // pixel-pair block

    // Stage weights once: 16*9*4 = 576 floats, transposed to [cin][k][c]
    for (int i = threadIdx.x; i < Cin * 9 * CPT; i += BLOCK) {
        const int cin = i / (9 * CPT);
        const int rem = i % (9 * CPT);
        const int k   = rem / CPT;
        const int c   = rem % CPT;
        reinterpret_cast<float*>(wl)[(cin * 9 + k) * CPT + c] =
            wt[((g * CPT + c) * Cin + cin) * 9 + k];
    }
    __syncthreads();

    // pixel-pair id: each thread does pixels (h, w0) and (h, w0+1)
    const int p  = pblk * BLOCK + threadIdx.x;    // 0..16383
    const int w0 = (p & 31) * 2;                  // 0,2,..,62
    const int h  = (p >> 5) & 63;
    const int b  = p >> 11;

    const int hm = max(h - 1, 0) * Wn;
    const int h0 = h * Wn;
    const int hp = min(h + 1, Hn - 1) * Wn;
    const int cm = max(w0 - 1, 0);
    const int c1 = w0;
    const int c2 = w0 + 1;
    const int c3 = min(w0 + 2, Wn - 1);

#pragma unroll 1
    for (int rep = 0; rep < REPS; ++rep) {
        // Opaque per-rep pointers: compiler cannot CSE loads across reps or
        // dead-store-eliminate earlier reps' stores (errata #17 pattern).
        const float* xo = x;
        float*       oo = out;
        asm volatile("" : "+s"(xo), "+s"(oo));

        float a0[CPT], a1[CPT];
#pragma unroll
        for (int c = 0; c < CPT; ++c) { a0[c] = 0.f; a1[c] = 0.f; }

        const float* xb = xo + b * (Cin * Hn * Wn);
#pragma unroll
        for (int cin = 0; cin < Cin; ++cin) {
            const float* xc = xb + cin * (Hn * Wn);
            float xr[3][4];
            xr[0][0] = xc[hm + cm]; xr[0][1] = xc[hm + c1]; xr[0][2] = xc[hm + c2]; xr[0][3] = xc[hm + c3];
            xr[1][0] = xc[h0 + cm]; xr[1][1] = xc[h0 + c1]; xr[1][2] = xc[h0 + c2]; xr[1][3] = xc[h0 + c3];
            xr[2][0] = xc[hp + cm]; xr[2][1] = xc[hp + c1]; xr[2][2] = xc[hp + c2]; xr[2][3] = xc[hp + c3];
#pragma unroll
            for (int kh = 0; kh < 3; ++kh) {
#pragma unroll
                for (int kw = 0; kw < 3; ++kw) {
                    const float4 wv = wl[cin * 9 + kh * 3 + kw];
                    const float xa = xr[kh][kw];       // pixel 0 tap
                    const float xv = xr[kh][kw + 1];   // pixel 1 tap
                    a0[0] = fmaxf(a0[0], fabsf(xa - wv.x));
                    a0[1] = fmaxf(a0[1], fabsf(xa - wv.y));
                    a0[2] = fmaxf(a0[2], fabsf(xa - wv.z));
                    a0[3] = fmaxf(a0[3], fabsf(xa - wv.w));
                    a1[0] = fmaxf(a1[0], fabsf(xv - wv.x));
                    a1[1] = fmaxf(a1[1], fabsf(xv - wv.y));
                    a1[2] = fmaxf(a1[2], fabsf(xv - wv.z));
                    a1[3] = fmaxf(a1[3], fabsf(xv - wv.w));
                }
            }
        }

        float* ob = oo + b * (Cout * Hn * Wn) + h0 + w0;
#pragma unroll
        for (int c = 0; c < CPT; ++c) {
            const int co = g * CPT + c;
            const float bi = bias[co];
            float2 v = make_float2(a0[c] + bi, a1[c] + bi);
            *reinterpret_cast<float2*>(ob + co * (Hn * Wn)) = v;
        }
    }
}

extern "C" void kernel_launch(void* const* d_in, const int* in_sizes, int n_in,
                              void* d_out, int out_size, void* d_ws, size_t ws_size,
                              hipStream_t stream) {
    const float* x    = (const float*)d_in[0];
    const float* wt   = (const float*)d_in[1];
    const float* bias = (const float*)d_in[2];
    float* out        = (float*)d_out;

    // grid: 8 cout-groups * (8*64*64/2 pixel-pairs / 256 threads) = 512 blocks
    const int pixel_pairs = Bn * Hn * Wn / 2;          // 16384
    const int grid = NG * (pixel_pairs / BLOCK);       // 512
    dist_conv_kernel<<<grid, BLOCK, 0, stream>>>(x, wt, bias, out);
}

// Round 8
// 65.052 us; speedup vs baseline: 2.1926x; 2.1926x over previous
//
#include <hip/hip_runtime.h>

// Dist_Conv2D_Dense: Chebyshev (L-inf) distance "conv".
// B=8, Cin=16, H=W=64, Cout=32, K=3, stride=1, edge-replicate pad.
// out[b][co][h][w] = max_{cin,kh,kw} |x[b][cin][clamp(h+kh-1)][clamp(w+kw-1)]
//                                    - wt[co][cin][kh][kw]|  + bias[co]
//
// Round-7 (resubmit): occupancy fix. Round-6 instrumentation showed warm
// kernel 12.1us, VALUBusy 53%, Occupancy 21% (512-block grid = 2 blocks/CU,
// grid-limited), bank conflicts 0, HBM 5% -> latency-stalled VALU kernel.
// This round: 1 pixel x 4 couts per thread -> 1024 blocks = 4/CU = 16
// waves/CU (2x TLP).

constexpr int Bn = 8, Cin = 16, Hn = 64, Wn = 64, Cout = 32;
constexpr int CPT = 4;            // couts per thread
constexpr int NG  = Cout / CPT;   // 8 cout groups
constexpr int BLOCK = 256;

__global__ __launch_bounds__(BLOCK, 4)   // 4 waves/EU min -> >=4 blocks/CU resident
void dist_conv_kernel(const float* __restrict__ x,
                      const float* __restrict__ wt,
                      const float* __restrict__ bias,
                      float* __restrict__ out) {
    // weights for this block's 4 couts: [cin*9 + k] -> float4 over couts
    __shared__ float4 wl[Cin * 9];

    const int g    = blockIdx.x & (NG - 1);   // cout group 0..7
    const int pblk = blockIdx.x >> 3;         // pixel block 0..127

    // Stage weights: 16*9*4 = 576 floats, transposed to [cin][k][c]
    for (int i = threadIdx.x; i < Cin * 9 * CPT; i += BLOCK) {
        const int cin = i / (9 * CPT);
        const int rem = i % (9 * CPT);
        const int k   = rem / CPT;
        const int c   = rem % CPT;
        reinterpret_cast<float*>(wl)[(cin * 9 + k) * CPT + c] =
            wt[((g * CPT + c) * Cin + cin) * 9 + k];
    }
    __syncthreads();

    // one pixel per thread
    const int p  = pblk * BLOCK + threadIdx.x;    // 0..32767
    const int w0 = p & 63;
    const int h  = (p >> 6) & 63;
    const int b  = p >> 12;

    const int hm = max(h - 1, 0) * Wn;
    const int h0 = h * Wn;
    const int hp = min(h + 1, Hn - 1) * Wn;
    const int cm = max(w0 - 1, 0);
    const int cp = min(w0 + 1, Wn - 1);

    float acc[CPT] = {0.f, 0.f, 0.f, 0.f};

    const float* xb = x + b * (Cin * Hn * Wn);
#pragma unroll
    for (int cin = 0; cin < Cin; ++cin) {
        const float* xc = xb + cin * (Hn * Wn);
        float xr[3][3];
        xr[0][0] = xc[hm + cm]; xr[0][1] = xc[hm + w0]; xr[0][2] = xc[hm + cp];
        xr[1][0] = xc[h0 + cm]; xr[1][1] = xc[h0 + w0]; xr[1][2] = xc[h0 + cp];
        xr[2][0] = xc[hp + cm]; xr[2][1] = xc[hp + w0]; xr[2][2] = xc[hp + cp];
#pragma unroll
        for (int kh = 0; kh < 3; ++kh) {
#pragma unroll
            for (int kw = 0; kw < 3; ++kw) {
                const float4 wv = wl[cin * 9 + kh * 3 + kw];
                const float xa = xr[kh][kw];
                acc[0] = fmaxf(acc[0], fabsf(xa - wv.x));
                acc[1] = fmaxf(acc[1], fabsf(xa - wv.y));
                acc[2] = fmaxf(acc[2], fabsf(xa - wv.z));
                acc[3] = fmaxf(acc[3], fabsf(xa - wv.w));
            }
        }
    }

    float* ob = out + b * (Cout * Hn * Wn) + h0 + w0;
#pragma unroll
    for (int c = 0; c < CPT; ++c) {
        const int co = g * CPT + c;
        ob[co * (Hn * Wn)] = acc[c] + bias[co];
    }
}

extern "C" void kernel_launch(void* const* d_in, const int* in_sizes, int n_in,
                              void* d_out, int out_size, void* d_ws, size_t ws_size,
                              hipStream_t stream) {
    const float* x    = (const float*)d_in[0];
    const float* wt   = (const float*)d_in[1];
    const float* bias = (const float*)d_in[2];
    float* out        = (float*)d_out;

    // grid: 8 cout-groups * (8*64*64 pixels / 256 threads) = 8*128 = 1024 blocks
    const int pixels = Bn * Hn * Wn;               // 32768
    const int grid   = NG * (pixels / BLOCK);      // 1024
    dist_conv_kernel<<<grid, BLOCK, 0, stream>>>(x, wt, bias, out);
}